// Round 1
// baseline (2484.438 us; speedup 1.0000x reference)
//
#include <hip/hip_runtime.h>

#define WROW 52   // 13 time slices * 4 feats per node

// ---------------- conv (2 layers) + edge-input projection -------------------
// 16 threads per node. cp: per-node scratch 160 floats:
//   [0..19] window (5 slices x 4), [32..127] h1 (3x32), [128..159] h2 (32)
__device__ __forceinline__ void conv_proj(
    int lane, int gid, float* cp,
    const float* __restrict__ cw1, const float* __restrict__ cb1,
    const float* __restrict__ cw2, const float* __restrict__ cb2,
    const float* __restrict__ ew1,
    float* __restrict__ an, float* __restrict__ bn)
{
  // conv1: out[tt][f] over tt=0..2, f=0..31 (96 outputs, 6 per thread)
  #pragma unroll
  for (int o = 0; o < 6; ++o) {
    int idx = lane + (o << 4);
    int tt = idx >> 5, f = idx & 31;
    float a = cb1[f];
    #pragma unroll
    for (int kt = 0; kt < 3; ++kt)
      #pragma unroll
      for (int d = 0; d < 4; ++d)
        a = fmaf(cp[(tt + kt) * 4 + d], cw1[(kt * 4 + d) * 32 + f], a);
    cp[32 + idx] = fmaxf(a, 0.f);
  }
  __syncthreads();
  // conv2: 32 outputs (2 per thread)
  #pragma unroll
  for (int o = 0; o < 2; ++o) {
    int f = lane + (o << 4);
    float a = cb2[f];
    #pragma unroll
    for (int kt = 0; kt < 3; ++kt)
      for (int f1 = 0; f1 < 32; ++f1)
        a = fmaf(cp[32 + kt * 32 + f1], cw2[(kt * 32 + f1) * 32 + f], a);
    cp[128 + f] = fmaxf(a, 0.f);
  }
  __syncthreads();
  // projection: an = h2 @ ew1[0:32], bn = h2 @ ew1[32:64]  (128 each)
  #pragma unroll
  for (int o = 0; o < 8; ++o) {
    int j = lane + (o << 4);
    float a = 0.f, bb = 0.f;
    for (int f = 0; f < 32; ++f) {
      float h = cp[128 + f];
      a  = fmaf(h, ew1[f * 128 + j], a);
      bb = fmaf(h, ew1[(32 + f) * 128 + j], bb);
    }
    an[gid * 128 + j] = a;
    bn[gid * 128 + j] = bb;
  }
}

// ---------------- k_init: transpose + step-0 conv/proj ---------------------
__global__ __launch_bounds__(256) void k_init(
    const float* __restrict__ ts,
    const float* __restrict__ cw1, const float* __restrict__ cb1,
    const float* __restrict__ cw2, const float* __restrict__ cb2,
    const float* __restrict__ ew1,
    float* __restrict__ win, float* __restrict__ an, float* __restrict__ bn)
{
  __shared__ float cp[16 * 160];
  int blk = blockIdx.x;
  int b = blk >> 2, n0 = (blk & 3) << 4;
  int tid = threadIdx.x;
  int ln = tid >> 4, lane = tid & 15;
  int n = n0 + ln;
  int gid = b * 64 + n;
  float* mycp = cp + ln * 160;
  for (int idx = lane; idx < 20; idx += 16) {
    int tt = idx >> 2, d = idx & 3;
    float v = ts[((b * 5 + tt) * 64 + n) * 4 + d];
    mycp[idx] = v;
    win[gid * WROW + idx] = v;   // slices 0..4
  }
  __syncthreads();
  conv_proj(lane, gid, mycp, cw1, cb1, cw2, cb2, ew1, an, bn);
}

// ---------------- k_edge: per (b,t) 64x128 @ 128x128 + relu + masked sum ---
__global__ __launch_bounds__(256) void k_edge(
    const float* __restrict__ an, const float* __restrict__ bn,
    const float* __restrict__ eb1, const float* __restrict__ ew2,
    const float* __restrict__ eb2, float* __restrict__ nm)
{
  __shared__ __align__(16) float s_h1[64][132];
  __shared__ float s_bt[128], s_eb2[128];
  __shared__ float s_red[16][132];
  int blk = blockIdx.x;
  int b = blk >> 6, t = blk & 63;
  int tid = threadIdx.x;
  if (tid < 128) {
    s_bt[tid]  = bn[(b * 64 + t) * 128 + tid] + eb1[tid];
    s_eb2[tid] = eb2[tid];
  }
  __syncthreads();
  // h1[s][i] = relu(an[s][i] + bt[i]) for all 64 sources (s==t masked later)
  for (int idx = tid; idx < 8192; idx += 256) {
    int s = idx >> 7, i = idx & 127;
    s_h1[s][i] = fmaxf(an[(b * 64 + s) * 128 + i] + s_bt[i], 0.f);
  }
  __syncthreads();

  // register-tiled GEMM: thread = (sg 0..15) x (jg 0..15); tile 4 src x 8 cols
  int sg = tid >> 4, jg = tid & 15;
  float acc[4][8];
  #pragma unroll
  for (int m = 0; m < 4; ++m)
    #pragma unroll
    for (int mm = 0; mm < 8; ++mm) acc[m][mm] = 0.f;

  const float* hrow0 = &s_h1[(sg << 2) + 0][0];
  const float* hrow1 = &s_h1[(sg << 2) + 1][0];
  const float* hrow2 = &s_h1[(sg << 2) + 2][0];
  const float* hrow3 = &s_h1[(sg << 2) + 3][0];
  const float* wbase = ew2 + (jg << 3);

  for (int k0 = 0; k0 < 128; k0 += 4) {
    float4 hv[4];
    hv[0] = *(const float4*)(hrow0 + k0);
    hv[1] = *(const float4*)(hrow1 + k0);
    hv[2] = *(const float4*)(hrow2 + k0);
    hv[3] = *(const float4*)(hrow3 + k0);
    #pragma unroll
    for (int kk = 0; kk < 4; ++kk) {
      const float* wr = wbase + (k0 + kk) * 128;
      float4 wa = *(const float4*)(wr);
      float4 wb = *(const float4*)(wr + 4);
      float wf[8] = {wa.x, wa.y, wa.z, wa.w, wb.x, wb.y, wb.z, wb.w};
      #pragma unroll
      for (int m = 0; m < 4; ++m) {
        float hh = ((const float*)&hv[m])[kk];
        #pragma unroll
        for (int mm = 0; mm < 8; ++mm)
          acc[m][mm] = fmaf(hh, wf[mm], acc[m][mm]);
      }
    }
  }

  // per-edge bias + relu, mask s==t, partial sum over this thread's 4 sources
  #pragma unroll
  for (int mm = 0; mm < 8; ++mm) {
    int j = (jg << 3) + mm;
    float bias = s_eb2[j];
    float v = 0.f;
    #pragma unroll
    for (int m = 0; m < 4; ++m) {
      int s = (sg << 2) + m;
      float y = acc[m][mm] + bias;
      if (s != t) v += fmaxf(y, 0.f);
    }
    s_red[sg][j] = v;
  }
  __syncthreads();
  if (tid < 128) {
    float v = 0.f;
    #pragma unroll
    for (int g = 0; g < 16; ++g) v += s_red[g][tid];
    nm[(b * 64 + t) * 128 + tid] = v;
  }
}

// ---------------- dense layer helper: Y = relu(X @ W + b), 16 rows ---------
__device__ __forceinline__ void layer16(const float (*Xs)[132], float (*Ys)[132],
                                        const float* __restrict__ W,
                                        const float* __restrict__ bias, int tid)
{
  int j = tid & 127, nh = tid >> 7;
  float acc[8] = {0.f,0.f,0.f,0.f,0.f,0.f,0.f,0.f};
  for (int i = 0; i < 128; ++i) {
    float w = W[i * 128 + j];
    #pragma unroll
    for (int q = 0; q < 8; ++q) acc[q] = fmaf(Xs[(nh << 3) + q][i], w, acc[q]);
  }
  float bj = bias[j];
  #pragma unroll
  for (int q = 0; q < 8; ++q) Ys[(nh << 3) + q][j] = fmaxf(acc[q] + bj, 0.f);
}

// ---------------- k_nd: node MLP + decoder + write nxt + next conv/proj ----
__global__ __launch_bounds__(256) void k_nd(
    int step,
    const float* __restrict__ nm,
    const float* __restrict__ nw1, const float* __restrict__ nb1,
    const float* __restrict__ nw2, const float* __restrict__ nb2,
    const float* __restrict__ dw1, const float* __restrict__ db1,
    const float* __restrict__ dw2, const float* __restrict__ db2,
    const float* __restrict__ ow,  const float* __restrict__ ob,
    const float* __restrict__ cw1, const float* __restrict__ cb1,
    const float* __restrict__ cw2, const float* __restrict__ cb2,
    const float* __restrict__ ew1,
    float* __restrict__ win, float* __restrict__ an, float* __restrict__ bn,
    float* __restrict__ out)
{
  __shared__ __align__(16) float X[16][132];
  __shared__ __align__(16) float Y[16][132];
  __shared__ float P[16][4];
  __shared__ float cp[16 * 160];
  int blk = blockIdx.x;
  int b = blk >> 2, n0 = (blk & 3) << 4;
  int tid = threadIdx.x;

  for (int idx = tid; idx < 2048; idx += 256) {
    int ln = idx >> 7, j = idx & 127;
    X[ln][j] = nm[((b * 64 + n0 + ln) * 128) + j];
  }
  if (tid < 64) {
    int ln = tid >> 2, d = tid & 3;
    P[ln][d] = win[(b * 64 + n0 + ln) * WROW + (step + 4) * 4 + d];
  }
  __syncthreads();
  layer16(X, Y, nw1, nb1, tid);   // node mlp 1
  __syncthreads();
  layer16(Y, X, nw2, nb2, tid);   // node mlp 2 -> node_msg in X
  __syncthreads();
  // dec1: Y = relu([P, X] @ dw1 + db1)
  {
    int j = tid & 127, nh = tid >> 7;
    float acc[8];
    #pragma unroll
    for (int q = 0; q < 8; ++q) {
      acc[q] = 0.f;
      #pragma unroll
      for (int d = 0; d < 4; ++d)
        acc[q] = fmaf(P[(nh << 3) + q][d], dw1[d * 128 + j], acc[q]);
    }
    const float* W = dw1 + 4 * 128;
    for (int i = 0; i < 128; ++i) {
      float w = W[i * 128 + j];
      #pragma unroll
      for (int q = 0; q < 8; ++q) acc[q] = fmaf(X[(nh << 3) + q][i], w, acc[q]);
    }
    float bj = db1[j];
    #pragma unroll
    for (int q = 0; q < 8; ++q) Y[(nh << 3) + q][j] = fmaxf(acc[q] + bj, 0.f);
  }
  __syncthreads();
  layer16(Y, X, dw2, db2, tid);   // dec2 -> X
  __syncthreads();
  // output head: nxt = X @ ow + ob + prev
  if (tid < 64) {
    int ln = tid >> 2, d = tid & 3;
    float a = ob[d] + P[ln][d];
    for (int i = 0; i < 128; ++i) a = fmaf(X[ln][i], ow[i * 4 + d], a);
    int n = n0 + ln, gid = b * 64 + n;
    win[gid * WROW + (step + 5) * 4 + d] = a;
    out[((b * 8 + step) * 64 + n) * 4 + d] = a;
    Y[ln][d] = a;                 // keep nxt in LDS for phase C
  }
  __syncthreads();
  if (step < 7) {
    int ln = tid >> 4, lane = tid & 15;
    int gid = b * 64 + n0 + ln;
    float* mycp = cp + ln * 160;
    // window slices step+1..step+4 from global, step+5 from LDS
    mycp[lane] = win[gid * WROW + (step + 1) * 4 + lane];
    if (lane < 4) mycp[16 + lane] = Y[ln][lane];
    __syncthreads();
    conv_proj(lane, gid, mycp, cw1, cb1, cw2, cb2, ew1, an, bn);
  }
}

extern "C" void kernel_launch(void* const* d_in, const int* in_sizes, int n_in,
                              void* d_out, int out_size, void* d_ws, size_t ws_size,
                              hipStream_t stream) {
  (void)in_sizes; (void)n_in; (void)out_size; (void)ws_size;
  const float* ts  = (const float*)d_in[0];
  const float* cw1 = (const float*)d_in[1];
  const float* cb1 = (const float*)d_in[2];
  const float* cw2 = (const float*)d_in[3];
  const float* cb2 = (const float*)d_in[4];
  const float* ew1 = (const float*)d_in[5];
  const float* eb1 = (const float*)d_in[6];
  const float* ew2 = (const float*)d_in[7];
  const float* eb2 = (const float*)d_in[8];
  const float* nw1 = (const float*)d_in[9];
  const float* nb1 = (const float*)d_in[10];
  const float* nw2 = (const float*)d_in[11];
  const float* nb2 = (const float*)d_in[12];
  const float* dw1 = (const float*)d_in[13];
  const float* db1 = (const float*)d_in[14];
  const float* dw2 = (const float*)d_in[15];
  const float* db2 = (const float*)d_in[16];
  const float* ow  = (const float*)d_in[17];
  const float* ob  = (const float*)d_in[18];
  float* out = (float*)d_out;
  float* ws  = (float*)d_ws;
  float* win = ws;                       // 128*64*52   = 425984 floats
  float* an  = win + 425984;             // 128*64*128  = 1048576
  float* bn  = an + 1048576;
  float* nmb = bn + 1048576;

  hipLaunchKernelGGL(k_init, dim3(512), dim3(256), 0, stream,
                     ts, cw1, cb1, cw2, cb2, ew1, win, an, bn);
  for (int k = 0; k < 8; ++k) {
    hipLaunchKernelGGL(k_edge, dim3(8192), dim3(256), 0, stream,
                       an, bn, eb1, ew2, eb2, nmb);
    hipLaunchKernelGGL(k_nd, dim3(512), dim3(256), 0, stream,
                       k, nmb, nw1, nb1, nw2, nb2, dw1, db1, dw2, db2,
                       ow, ob, cw1, cb1, cw2, cb2, ew1, win, an, bn, out);
  }
}

// Round 2
// 934.179 us; speedup vs baseline: 2.6595x; 2.6595x over previous
//
#include <hip/hip_runtime.h>

#define WROW 52   // 13 time slices * 4 feats per node

typedef _Float16 half_t;
typedef _Float16 half8 __attribute__((ext_vector_type(8)));
typedef float f32x4 __attribute__((ext_vector_type(4)));

// ---------------- conv (2 layers) + edge-input projection -------------------
__device__ __forceinline__ void conv_proj(
    int lane, int gid, float* cp,
    const float* __restrict__ cw1, const float* __restrict__ cb1,
    const float* __restrict__ cw2, const float* __restrict__ cb2,
    const float* __restrict__ ew1,
    float* __restrict__ an, float* __restrict__ bn)
{
  #pragma unroll
  for (int o = 0; o < 6; ++o) {
    int idx = lane + (o << 4);
    int tt = idx >> 5, f = idx & 31;
    float a = cb1[f];
    #pragma unroll
    for (int kt = 0; kt < 3; ++kt)
      #pragma unroll
      for (int d = 0; d < 4; ++d)
        a = fmaf(cp[(tt + kt) * 4 + d], cw1[(kt * 4 + d) * 32 + f], a);
    cp[32 + idx] = fmaxf(a, 0.f);
  }
  __syncthreads();
  #pragma unroll
  for (int o = 0; o < 2; ++o) {
    int f = lane + (o << 4);
    float a = cb2[f];
    #pragma unroll
    for (int kt = 0; kt < 3; ++kt)
      for (int f1 = 0; f1 < 32; ++f1)
        a = fmaf(cp[32 + kt * 32 + f1], cw2[(kt * 32 + f1) * 32 + f], a);
    cp[128 + f] = fmaxf(a, 0.f);
  }
  __syncthreads();
  #pragma unroll
  for (int o = 0; o < 8; ++o) {
    int j = lane + (o << 4);
    float a = 0.f, bb = 0.f;
    for (int f = 0; f < 32; ++f) {
      float h = cp[128 + f];
      a  = fmaf(h, ew1[f * 128 + j], a);
      bb = fmaf(h, ew1[(32 + f) * 128 + j], bb);
    }
    an[gid * 128 + j] = a;
    bn[gid * 128 + j] = bb;
  }
}

// ---------------- k_init: transpose + step-0 conv/proj ---------------------
__global__ __launch_bounds__(256) void k_init(
    const float* __restrict__ ts,
    const float* __restrict__ cw1, const float* __restrict__ cb1,
    const float* __restrict__ cw2, const float* __restrict__ cb2,
    const float* __restrict__ ew1,
    float* __restrict__ win, float* __restrict__ an, float* __restrict__ bn)
{
  __shared__ float cp[16 * 160];
  int blk = blockIdx.x;
  int b = blk >> 2, n0 = (blk & 3) << 4;
  int tid = threadIdx.x;
  int ln = tid >> 4, lane = tid & 15;
  int n = n0 + ln;
  int gid = b * 64 + n;
  float* mycp = cp + ln * 160;
  for (int idx = lane; idx < 20; idx += 16) {
    int tt = idx >> 2, d = idx & 3;
    float v = ts[((b * 5 + tt) * 64 + n) * 4 + d];
    mycp[idx] = v;
    win[gid * WROW + idx] = v;
  }
  __syncthreads();
  conv_proj(lane, gid, mycp, cw1, cb1, cw2, cb2, ew1, an, bn);
}

// ---------------- k_bsplit: ew2 -> fp16 hi/lo in MFMA-fragment layout ------
__global__ __launch_bounds__(256) void k_bsplit(
    const float* __restrict__ ew2, half_t* __restrict__ Bh, half_t* __restrict__ Bl)
{
  int g = blockIdx.x * 256 + threadIdx.x;   // 0..16383 : k*128+col
  int k = g >> 7, col = g & 127;
  float x = ew2[g];
  _Float16 hi = (_Float16)x;
  float lo = x - (float)hi;
  int c = col >> 4, kb = k >> 5, kk = k & 31;
  int lane = ((kk >> 3) << 4) | (col & 15);
  int j = kk & 7;
  int idx = ((c * 4 + kb) * 64 + lane) * 8 + j;
  Bh[idx] = hi;
  Bl[idx] = (_Float16)lo;
}

// ---------------- k_edge_mfma: per (b,t) 64x128 @ 128x128 via f16-split ----
// C = 1024 * (Ah@Bh + Ah@Bl + Al@Bh), A = relu(an+bt) * 2^-10
__global__ __launch_bounds__(256) void k_edge_mfma(
    const float* __restrict__ an, const float* __restrict__ bn,
    const float* __restrict__ eb1, const float* __restrict__ eb2,
    const half_t* __restrict__ Bh, const half_t* __restrict__ Bl,
    float* __restrict__ nm)
{
  __shared__ __align__(16) half_t sAh[8192];   // 16 KB, fragment-permuted
  __shared__ __align__(16) half_t sAl[8192];   // 16 KB
  __shared__ float s_bt[128], s_eb2[128];
  __shared__ float s_part[2][128];
  int blk = blockIdx.x;
  int b = blk >> 6, t = blk & 63;
  int tid = threadIdx.x;
  if (tid < 128) {
    s_bt[tid]  = bn[(b * 64 + t) * 128 + tid] + eb1[tid];
    s_eb2[tid] = eb2[tid];
  }
  __syncthreads();

  const float SC = 0.0009765625f;   // 2^-10
  // split phase: unit u = (s, kb8) -> 8 consecutive k of row s, one b128 write
  #pragma unroll
  for (int it = 0; it < 4; ++it) {
    int u = tid + it * 256;
    int s = u >> 4, kb8 = u & 15;
    const float* ap = an + (((b << 6) + s) << 7) + (kb8 << 3);
    float4 x0 = *(const float4*)ap;
    float4 x1 = *(const float4*)(ap + 4);
    float4 b0 = *(const float4*)(s_bt + (kb8 << 3));
    float4 b1 = *(const float4*)(s_bt + (kb8 << 3) + 4);
    float xs[8] = {x0.x, x0.y, x0.z, x0.w, x1.x, x1.y, x1.z, x1.w};
    float bs[8] = {b0.x, b0.y, b0.z, b0.w, b1.x, b1.y, b1.z, b1.w};
    half8 hv, lv;
    #pragma unroll
    for (int i = 0; i < 8; ++i) {
      float h = fmaxf(xs[i] + bs[i], 0.f) * SC;
      _Float16 hi = (_Float16)h;
      hv[i] = hi;
      lv[i] = (_Float16)(h - (float)hi);
    }
    int kb = kb8 >> 2;
    int lane = ((kb8 & 3) << 4) | (s & 15);
    int base = (((s >> 4) * 4 + kb) * 64 + lane) * 8;
    *(half8*)(sAh + base) = hv;
    *(half8*)(sAl + base) = lv;
  }
  __syncthreads();

  // MFMA phase: wave w -> rows (w>>1)*32..+31, cols (w&1)*64..+63
  int w = tid >> 6, lane = tid & 63;
  int wr = w >> 1, wc = w & 1;
  f32x4 acc[2][4];
  #pragma unroll
  for (int rr = 0; rr < 2; ++rr)
    #pragma unroll
    for (int cc = 0; cc < 4; ++cc)
      acc[rr][cc] = (f32x4){0.f, 0.f, 0.f, 0.f};

  #pragma unroll
  for (int kb = 0; kb < 4; ++kb) {
    half8 ah[2], al[2];
    #pragma unroll
    for (int rr = 0; rr < 2; ++rr) {
      int r = wr * 2 + rr;
      ah[rr] = *(half8*)(sAh + ((r * 4 + kb) * 64 + lane) * 8);
      al[rr] = *(half8*)(sAl + ((r * 4 + kb) * 64 + lane) * 8);
    }
    #pragma unroll
    for (int cc = 0; cc < 4; ++cc) {
      int c = wc * 4 + cc;
      half8 bh = *(const half8*)(Bh + ((c * 4 + kb) * 64 + lane) * 8);
      half8 bl = *(const half8*)(Bl + ((c * 4 + kb) * 64 + lane) * 8);
      #pragma unroll
      for (int rr = 0; rr < 2; ++rr) {
        acc[rr][cc] = __builtin_amdgcn_mfma_f32_16x16x32_f16(ah[rr], bh, acc[rr][cc], 0, 0, 0);
        acc[rr][cc] = __builtin_amdgcn_mfma_f32_16x16x32_f16(ah[rr], bl, acc[rr][cc], 0, 0, 0);
        acc[rr][cc] = __builtin_amdgcn_mfma_f32_16x16x32_f16(al[rr], bh, acc[rr][cc], 0, 0, 0);
      }
    }
  }

  // epilogue: bias + relu per (s,col), mask s==t, sum rows
  float csum[4] = {0.f, 0.f, 0.f, 0.f};
  int colbase = lane & 15;
  int rowoff  = (lane >> 4) * 4;
  #pragma unroll
  for (int cc = 0; cc < 4; ++cc) {
    int col = (wc * 4 + cc) * 16 + colbase;
    float bias = s_eb2[col];
    #pragma unroll
    for (int rr = 0; rr < 2; ++rr) {
      int sbase = (wr * 2 + rr) * 16 + rowoff;
      #pragma unroll
      for (int q = 0; q < 4; ++q) {
        int s = sbase + q;
        float y = acc[rr][cc][q] * 1024.f + bias;
        if (s != t) csum[cc] += fmaxf(y, 0.f);
      }
    }
  }
  #pragma unroll
  for (int cc = 0; cc < 4; ++cc) {
    csum[cc] += __shfl_xor(csum[cc], 16, 64);
    csum[cc] += __shfl_xor(csum[cc], 32, 64);
  }
  if (lane < 16) {
    #pragma unroll
    for (int cc = 0; cc < 4; ++cc)
      s_part[wr][(wc * 4 + cc) * 16 + lane] = csum[cc];
  }
  __syncthreads();
  if (tid < 128)
    nm[(b * 64 + t) * 128 + tid] = s_part[0][tid] + s_part[1][tid];
}

// ---------------- dense layer helper: Y = relu(X @ W + b), 16 rows ---------
__device__ __forceinline__ void layer16(const float (*Xs)[132], float (*Ys)[132],
                                        const float* __restrict__ W,
                                        const float* __restrict__ bias, int tid)
{
  int j = tid & 127, nh = tid >> 7;
  float acc[8] = {0.f,0.f,0.f,0.f,0.f,0.f,0.f,0.f};
  for (int i = 0; i < 128; ++i) {
    float w = W[i * 128 + j];
    #pragma unroll
    for (int q = 0; q < 8; ++q) acc[q] = fmaf(Xs[(nh << 3) + q][i], w, acc[q]);
  }
  float bj = bias[j];
  #pragma unroll
  for (int q = 0; q < 8; ++q) Ys[(nh << 3) + q][j] = fmaxf(acc[q] + bj, 0.f);
}

// ---------------- k_nd: node MLP + decoder + write nxt + next conv/proj ----
__global__ __launch_bounds__(256) void k_nd(
    int step,
    const float* __restrict__ nm,
    const float* __restrict__ nw1, const float* __restrict__ nb1,
    const float* __restrict__ nw2, const float* __restrict__ nb2,
    const float* __restrict__ dw1, const float* __restrict__ db1,
    const float* __restrict__ dw2, const float* __restrict__ db2,
    const float* __restrict__ ow,  const float* __restrict__ ob,
    const float* __restrict__ cw1, const float* __restrict__ cb1,
    const float* __restrict__ cw2, const float* __restrict__ cb2,
    const float* __restrict__ ew1,
    float* __restrict__ win, float* __restrict__ an, float* __restrict__ bn,
    float* __restrict__ out)
{
  __shared__ __align__(16) float X[16][132];
  __shared__ __align__(16) float Y[16][132];
  __shared__ float P[16][4];
  __shared__ float cp[16 * 160];
  int blk = blockIdx.x;
  int b = blk >> 2, n0 = (blk & 3) << 4;
  int tid = threadIdx.x;

  for (int idx = tid; idx < 2048; idx += 256) {
    int ln = idx >> 7, j = idx & 127;
    X[ln][j] = nm[((b * 64 + n0 + ln) * 128) + j];
  }
  if (tid < 64) {
    int ln = tid >> 2, d = tid & 3;
    P[ln][d] = win[(b * 64 + n0 + ln) * WROW + (step + 4) * 4 + d];
  }
  __syncthreads();
  layer16(X, Y, nw1, nb1, tid);
  __syncthreads();
  layer16(Y, X, nw2, nb2, tid);
  __syncthreads();
  {
    int j = tid & 127, nh = tid >> 7;
    float acc[8];
    #pragma unroll
    for (int q = 0; q < 8; ++q) {
      acc[q] = 0.f;
      #pragma unroll
      for (int d = 0; d < 4; ++d)
        acc[q] = fmaf(P[(nh << 3) + q][d], dw1[d * 128 + j], acc[q]);
    }
    const float* W = dw1 + 4 * 128;
    for (int i = 0; i < 128; ++i) {
      float w = W[i * 128 + j];
      #pragma unroll
      for (int q = 0; q < 8; ++q) acc[q] = fmaf(X[(nh << 3) + q][i], w, acc[q]);
    }
    float bj = db1[j];
    #pragma unroll
    for (int q = 0; q < 8; ++q) Y[(nh << 3) + q][j] = fmaxf(acc[q] + bj, 0.f);
  }
  __syncthreads();
  layer16(Y, X, dw2, db2, tid);
  __syncthreads();
  if (tid < 64) {
    int ln = tid >> 2, d = tid & 3;
    float a = ob[d] + P[ln][d];
    for (int i = 0; i < 128; ++i) a = fmaf(X[ln][i], ow[i * 4 + d], a);
    int n = n0 + ln, gid = b * 64 + n;
    win[gid * WROW + (step + 5) * 4 + d] = a;
    out[((b * 8 + step) * 64 + n) * 4 + d] = a;
    Y[ln][d] = a;
  }
  __syncthreads();
  if (step < 7) {
    int ln = tid >> 4, lane = tid & 15;
    int gid = b * 64 + n0 + ln;
    float* mycp = cp + ln * 160;
    mycp[lane] = win[gid * WROW + (step + 1) * 4 + lane];
    if (lane < 4) mycp[16 + lane] = Y[ln][lane];
    __syncthreads();
    conv_proj(lane, gid, mycp, cw1, cb1, cw2, cb2, ew1, an, bn);
  }
}

extern "C" void kernel_launch(void* const* d_in, const int* in_sizes, int n_in,
                              void* d_out, int out_size, void* d_ws, size_t ws_size,
                              hipStream_t stream) {
  (void)in_sizes; (void)n_in; (void)out_size; (void)ws_size;
  const float* ts  = (const float*)d_in[0];
  const float* cw1 = (const float*)d_in[1];
  const float* cb1 = (const float*)d_in[2];
  const float* cw2 = (const float*)d_in[3];
  const float* cb2 = (const float*)d_in[4];
  const float* ew1 = (const float*)d_in[5];
  const float* eb1 = (const float*)d_in[6];
  const float* ew2 = (const float*)d_in[7];
  const float* eb2 = (const float*)d_in[8];
  const float* nw1 = (const float*)d_in[9];
  const float* nb1 = (const float*)d_in[10];
  const float* nw2 = (const float*)d_in[11];
  const float* nb2 = (const float*)d_in[12];
  const float* dw1 = (const float*)d_in[13];
  const float* db1 = (const float*)d_in[14];
  const float* dw2 = (const float*)d_in[15];
  const float* db2 = (const float*)d_in[16];
  const float* ow  = (const float*)d_in[17];
  const float* ob  = (const float*)d_in[18];
  float* out = (float*)d_out;
  float* ws  = (float*)d_ws;
  float* win = ws;                       // 425984 floats
  float* an  = win + 425984;             // 1048576
  float* bn  = an + 1048576;             // 1048576
  float* nmb = bn + 1048576;             // 1048576
  half_t* Bh = (half_t*)(nmb + 1048576); // 16384 halves (8192 floats)
  half_t* Bl = Bh + 16384;               // 16384 halves

  hipLaunchKernelGGL(k_bsplit, dim3(64), dim3(256), 0, stream, ew2, Bh, Bl);
  hipLaunchKernelGGL(k_init, dim3(512), dim3(256), 0, stream,
                     ts, cw1, cb1, cw2, cb2, ew1, win, an, bn);
  for (int k = 0; k < 8; ++k) {
    hipLaunchKernelGGL(k_edge_mfma, dim3(8192), dim3(256), 0, stream,
                       an, bn, eb1, eb2, Bh, Bl, nmb);
    hipLaunchKernelGGL(k_nd, dim3(512), dim3(256), 0, stream,
                       k, nmb, nw1, nb1, nw2, nb2, dw1, db1, dw2, db2,
                       ow, ob, cw1, cb1, cw2, cb2, ew1, win, an, bn, out);
  }
}